// Round 11
// baseline (742.713 us; speedup 1.0000x reference)
//
#include <hip/hip_runtime.h>
#include <hip/hip_bf16.h>

// Shapes
#define BB   64
#define NN   512
#define EE   2048
#define FINK 300
#define DD   256
#define BN_TOT (BB*NN)    // 32768
#define BE_TOT (BB*EE)    // 131072
#define EPSF 1e-5f

using bf16 = __hip_bfloat16;
typedef unsigned short u16;
typedef __attribute__((ext_vector_type(8))) short short8;
typedef __attribute__((ext_vector_type(4))) float f32x4;

__device__ __forceinline__ float tf(float x) { return x; }
__device__ __forceinline__ float tf(bf16 x)  { return __bfloat162float(x); }
__device__ __forceinline__ void  stv(float* p, float v) { *p = v; }
__device__ __forceinline__ void  stv(bf16*  p, float v) { *p = __float2bfloat16(v); }

__device__ __forceinline__ u16 f2bu(float f) {
    bf16 b = __float2bfloat16(f);
    return *(u16*)&b;
}

// Direct global->LDS DMA, 16B per lane. LDS dst = wave-uniform base + lane*16.
__device__ __forceinline__ void gload16(const void* g, void* l)
{
    __builtin_amdgcn_global_load_lds((const __attribute__((address_space(1))) void*)g,
                                     (__attribute__((address_space(3))) void*)l, 16, 0, 0);
}

// Int dtype probe: lengths[1] as int32 is in [256,512] iff int32 storage;
// it is the zero hi-word of lengths[0] iff int64 (LE).
__global__ void detect_kernel(const int* __restrict__ lengths, int* __restrict__ flags)
{
    flags[1] = (lengths[1] == 0) ? 1 : 0;
}

__global__ void conv_i(const void* __restrict__ src, int* __restrict__ dst, int n,
                       const int* __restrict__ flags)
{
    int i = blockIdx.x * 256 + threadIdx.x;
    if (i >= n) return;
    const int* s = (const int*)src;
    dst[i] = s[flags[1] ? (i << 1) : i];
}

// f32 -> bf16 flat
__global__ void conv_f2b(const float* __restrict__ src, u16* __restrict__ dst, int n)
{
    int i = blockIdx.x * 256 + threadIdx.x;
    if (i < n) dst[i] = f2bu(src[i]);
}

// f32 (rows x sk) -> bf16 (rows x dk) zero-padded
__global__ void conv_pad(const float* __restrict__ src, u16* __restrict__ dst, int rows,
                         int sk, int dk)
{
    int i = blockIdx.x * 256 + threadIdx.x;
    if (i >= rows * dk) return;
    int r = i / dk, c = i - r * dk;
    dst[i] = (c < sk) ? f2bu(src[r * sk + c]) : 0;
}

// W3[:, :256] (stride 512) -> bf16 256x256
__global__ void conv_w3a(const float* __restrict__ W3, u16* __restrict__ dst)
{
    int i = blockIdx.x * 256 + threadIdx.x;   // 65536 total
    int r = i >> 8, c = i & 255;
    dst[i] = f2bu(W3[r * 512 + c]);
}

// ---------------------------------------------------------------------------
// m97-style MFMA GEMM: C[m,n] = sum_k A[m,k]*W[n*ldw+k] (+bias)
// MODE 0: plain store; MODE 1: relu; MODE 2: qkv-split epilogue —
//   n<512 -> qkb[m*512+n] (u16), n>=512 -> vt[((b*4+h)*64+d)*512+node] (u16)
// A, W bf16 (u16) row-major; tile 128x128, 4 waves, K-step 32.
// Staging via global_load_lds width=16 into unpadded [128][32] LDS tiles.
// ---------------------------------------------------------------------------
template<typename TC, int MODE>
__global__ __launch_bounds__(256)
void gemm_bf(const u16* __restrict__ A, const u16* __restrict__ W,
             const float* __restrict__ bias, TC* __restrict__ C,
             u16* __restrict__ vt, int M, int N, int K, int lda, int ldw)
{
    __shared__ u16 As[128 * 32];
    __shared__ u16 Ws[128 * 32];

    const int m0 = blockIdx.y * 128;
    const int n0 = blockIdx.x * 128;
    const int tid  = threadIdx.x;
    const int lane = tid & 63;
    const int wv   = tid >> 6;
    const int fr   = lane & 15;
    const int q8   = (lane >> 4) * 8;
    const int mb   = (wv >> 1) * 64;
    const int nb   = (wv & 1) * 64;

    const int c8  = (lane & 3) * 8;     // k sub-offset (staging)

    f32x4 acc[4][4];
#pragma unroll
    for (int i = 0; i < 4; i++)
#pragma unroll
        for (int j = 0; j < 4; j++) acc[i][j] = (f32x4){0.f, 0.f, 0.f, 0.f};

    const int r16 = lane >> 2;
    for (int k0 = 0; k0 < K; k0 += 32) {
        __syncthreads();
#pragma unroll
        for (int j = 0; j < 2; j++) {
            int rowA = m0 + wv * 32 + j * 16 + r16;
            int rowW = n0 + wv * 32 + j * 16 + r16;
            gload16(A + (size_t)rowA * lda + k0 + c8, &As[(wv * 32 + j * 16) * 32]);
            gload16(W + (size_t)rowW * ldw + k0 + c8, &Ws[(wv * 32 + j * 16) * 32]);
        }
        __syncthreads();

        short8 af[4], bf[4];
#pragma unroll
        for (int i = 0; i < 4; i++) af[i] = *(const short8*)&As[(mb + i * 16 + fr) * 32 + q8];
#pragma unroll
        for (int j = 0; j < 4; j++) bf[j] = *(const short8*)&Ws[(nb + j * 16 + fr) * 32 + q8];
#pragma unroll
        for (int i = 0; i < 4; i++)
#pragma unroll
            for (int j = 0; j < 4; j++)
                acc[i][j] = __builtin_amdgcn_mfma_f32_16x16x32_bf16(af[i], bf[j], acc[i][j], 0, 0, 0);
    }

#pragma unroll
    for (int i = 0; i < 4; i++) {
#pragma unroll
        for (int j = 0; j < 4; j++) {
            int gn = n0 + nb + j * 16 + fr;
            float bv = bias ? bias[gn] : 0.f;
#pragma unroll
            for (int r = 0; r < 4; r++) {
                int gm = m0 + mb + i * 16 + (lane >> 4) * 4 + r;
                float v = acc[i][j][r] + bv;
                if (MODE == 1) v = fmaxf(v, 0.f);
                if (MODE == 2) {
                    if (gn < 512) {
                        ((u16*)C)[(size_t)gm * 512 + gn] = f2bu(v);
                    } else {
                        int d = gn - 512, hh = d >> 6, dd = d & 63;
                        int bq = gm >> 9, node = gm & 511;
                        vt[(((size_t)bq * 4 + hh) * 64 + dd) * 512 + node] = f2bu(v);
                    }
                } else {
                    stv(&C[(size_t)gm * N + gn], v);
                }
            }
        }
    }
}

// M = W3b @ W2 (256 x 64) f32+bf16; sb[d] = row-sum of W3b.
__global__ void prep_M(const float* __restrict__ W3, const float* __restrict__ W2,
                       u16* __restrict__ Mb, float* __restrict__ sb)
{
    int d = blockIdx.x, a = threadIdx.x;
    float s = 0.f;
    for (int j = 0; j < 256; j++)
        s += W3[d * 512 + 256 + j] * W2[j * 64 + a];
    Mb[d * 64 + a] = f2bu(s);
    if (a == 0) {
        float t = 0.f;
        for (int j = 0; j < 256; j++) t += W3[d * 512 + 256 + j];
        sb[d] = t;
    }
}

// ---------------------------------------------------------------------------
// Per-batch counting sort of edges by column. One block per batch, 512 thr.
// ---------------------------------------------------------------------------
__global__ __launch_bounds__(512)
void sort_edges(const int* __restrict__ ecol, float* __restrict__ deg,
                int* __restrict__ node_off, int* __restrict__ sorted)
{
    const int b = blockIdx.x;
    const int t = threadIdx.x;
    const int base = b * EE;
    __shared__ int cnt[512];
    __shared__ int tmp[512];
    __shared__ int off2[512];

    cnt[t] = 0;
    __syncthreads();
    for (int e = t; e < EE; e += 512) atomicAdd(&cnt[ecol[base + e]], 1);
    __syncthreads();

    int v = cnt[t];
    deg[b * NN + t] = (float)(v + 1);
    tmp[t] = v;
    __syncthreads();
    for (int s = 1; s < 512; s <<= 1) {
        int y = (t >= s) ? tmp[t - s] : 0;
        __syncthreads();
        tmp[t] += y;
        __syncthreads();
    }
    int excl = tmp[t] - v;
    node_off[b * NN + t] = excl;
    off2[t] = excl;
    __syncthreads();
    for (int e = t; e < EE; e += 512) {
        int c = ecol[base + e];
        int pos = atomicAdd(&off2[c], 1);
        sorted[base + pos] = e;
    }
}

// ---------------------------------------------------------------------------
// Gather aggregation (no atomics): one block per node, 256 threads.
// ---------------------------------------------------------------------------
__global__ __launch_bounds__(256)
void edge_gather(const int* __restrict__ erow, const int* __restrict__ sorted,
                 const int* __restrict__ node_off, const float* __restrict__ deg,
                 const float* __restrict__ y1, const float* __restrict__ eattr,
                 float* __restrict__ agg1, u16* __restrict__ eaggb)
{
    const int j = blockIdx.x;
    const int b = j >> 9;
    const int c = j & 511;
    const int t = threadIdx.x;
    const int start = node_off[j];
    const int end   = (c == 511) ? EE : node_off[j + 1];
    const float dc = deg[j];

    float acc  = 0.f;
    float acce = 0.f;
    for (int i = start; i < end; i++) {
        int e  = sorted[b * EE + i];
        int eg = b * EE + e;
        int rg = b * NN + erow[eg];
        float norm = rsqrtf(deg[rg] * dc);
        acc += norm * y1[(size_t)rg * 256 + t];
        if (t < 64) acce += norm * eattr[(size_t)eg * 64 + t];
    }
    agg1[(size_t)j * 256 + t] = acc;
    if (t < 64) eaggb[(size_t)j * 64 + t] = f2bu(acce);
}

// h = tanh((agg1 + aggM + (y1+sb)/deg)/deg + bias) * mask -> aggM in place
__global__ void gcn_finalize(const float* __restrict__ agg1, float* __restrict__ aggM,
                             const float* __restrict__ y1, const float* __restrict__ sb,
                             const float* __restrict__ deg, const float* __restrict__ gcn_bias,
                             const int* __restrict__ lengths)
{
    size_t idx = (size_t)blockIdx.x * 256 + threadIdx.x;
    int j = (int)(idx >> 8);
    int d = (int)(idx & 255);
    float dg = deg[j];
    float a  = (agg1[idx] + aggM[idx] + (y1[idx] + sb[d]) / dg) / dg;
    float h  = tanhf(a + gcn_bias[d]);
    int b = j >> 9, p = j & 511;
    if (p >= lengths[b]) h = 0.f;
    aggM[idx] = h;
}

__global__ void bn_stats(const float* __restrict__ X, float* __restrict__ sums,
                         float* __restrict__ sumsq, int R)
{
    int t = threadIdx.x;
    float s = 0.f, q = 0.f;
    for (int r = blockIdx.x; r < R; r += gridDim.x) {
        float v = X[(size_t)r * DD + t];
        s += v; q += v * v;
    }
    atomicAdd(&sums[t], s);
    atomicAdd(&sumsq[t], q);
}

// X normalized in place; optional bf16 duplicate (GEMM A input)
__global__ void bn_apply(float* __restrict__ X, const float* __restrict__ sums,
                         const float* __restrict__ sumsq, const float* __restrict__ g,
                         const float* __restrict__ bt, int R, u16* __restrict__ dup)
{
    size_t idx = (size_t)blockIdx.x * 256 + threadIdx.x;
    int d = (int)(idx & 255);
    float invR = 1.f / (float)R;
    float m   = sums[d] * invR;
    float var = sumsq[d] * invR - m * m;
    float v = (X[idx] - m) * rsqrtf(fmaxf(var, 0.f) + EPSF) * g[d] + bt[d];
    X[idx] = v;
    if (dup) dup[idx] = f2bu(v);
}

// ---------------------------------------------------------------------------
// MFMA flash attention. Grid 2048: bh = bid & 255 (XCD-swizzle: same (b,h)
// -> same bid%8 -> same XCD L2), qt = bid >> 8.
// qkb: (BN,512)=[q|k] bf16 row-major; vt: [b,h,d,node] bf16 (pre-transposed
// by the in_proj GEMM epilogue) -> V stage is plain b128 copies, no unpack.
// ---------------------------------------------------------------------------
__global__ __launch_bounds__(256)
void attn_mfma(const u16* __restrict__ qkb, const u16* __restrict__ vt,
               u16* __restrict__ out)
{
    const int bh = blockIdx.x & 255;
    const int qt = blockIdx.x >> 8;
    const int b  = bh >> 2;
    const int h  = bh & 3;

    const int tid  = threadIdx.x;
    const int lane = tid & 63;
    const int wv   = tid >> 6;
    const int fr   = lane & 15;
    const int quad = lane >> 4;
    const int q8   = quad * 8;

    __shared__ u16 Qs[64][72];     // 9.2 KB
    __shared__ u16 Ks[128][72];    // 18.4 KB
    __shared__ u16 Vts[64][136];   // 17.4 KB (V^T chunk: [d][128 keys])
    __shared__ u16 Ps[64][136];    // 17.4 KB

    const size_t bb = (size_t)(b * NN);
    const u16* vtb = vt + ((size_t)bh * 64) * 512;

    // stage Q tile (rows qt*64.., cols h*64..)
#pragma unroll
    for (int i = 0; i < 2; i++) {
        int idx = i * 256 + tid;            // 0..511
        int r = idx >> 3, seg = idx & 7;
        uint4 u = *((const uint4*)(qkb + (bb + qt * 64 + r) * 512 + h * 64) + seg);
        *(uint4*)&Qs[r][seg * 8] = u;
    }

    f32x4 O[4];
#pragma unroll
    for (int t = 0; t < 4; t++) O[t] = (f32x4){0.f, 0.f, 0.f, 0.f};
    float m_i[4] = {-1e30f, -1e30f, -1e30f, -1e30f};
    float l_i[4] = {0.f, 0.f, 0.f, 0.f};

    for (int c = 0; c < 4; c++) {
        __syncthreads();
        // stage K chunk (128 rows x 64 d)
#pragma unroll
        for (int i = 0; i < 4; i++) {
            int idx = i * 256 + tid;        // 0..1023
            int r = idx >> 3, seg = idx & 7;
            uint4 u = *((const uint4*)(qkb + (bb + c * 128 + r) * 512 + 256 + h * 64) + seg);
            *(uint4*)&Ks[r][seg * 8] = u;
        }
        // stage V^T chunk (64 d-rows x 128 keys) — 1024 uint4 copies
#pragma unroll
        for (int i = 0; i < 4; i++) {
            int idx = i * 256 + tid;        // 0..1023
            int r = idx >> 4, seg = idx & 15;
            uint4 u = *((const uint4*)(vtb + (size_t)r * 512 + c * 128) + seg);
            *(uint4*)&Vts[r][seg * 8] = u;
        }
        __syncthreads();

        f32x4 S[8];
#pragma unroll
        for (int t = 0; t < 8; t++) S[t] = (f32x4){0.f, 0.f, 0.f, 0.f};
#pragma unroll
        for (int ks = 0; ks < 2; ks++) {
            short8 aq = *(const short8*)&Qs[wv * 16 + fr][ks * 32 + q8];
#pragma unroll
            for (int t = 0; t < 8; t++) {
                short8 bk = *(const short8*)&Ks[t * 16 + fr][ks * 32 + q8];
                S[t] = __builtin_amdgcn_mfma_f32_16x16x32_bf16(aq, bk, S[t], 0, 0, 0);
            }
        }

        float mc[4];
#pragma unroll
        for (int r = 0; r < 4; r++) {
            float mm = -1e30f;
#pragma unroll
            for (int t = 0; t < 8; t++) { S[t][r] *= 0.125f; mm = fmaxf(mm, S[t][r]); }
            mc[r] = mm;
        }
#pragma unroll
        for (int msk = 1; msk < 16; msk <<= 1)
#pragma unroll
            for (int r = 0; r < 4; r++) mc[r] = fmaxf(mc[r], __shfl_xor(mc[r], msk));

        float alpha[4], ls[4];
#pragma unroll
        for (int r = 0; r < 4; r++) {
            float mn = fmaxf(m_i[r], mc[r]);
            alpha[r] = __expf(m_i[r] - mn);
            m_i[r] = mn;
            ls[r] = 0.f;
        }
#pragma unroll
        for (int t = 0; t < 8; t++)
#pragma unroll
            for (int r = 0; r < 4; r++) {
                float p = __expf(S[t][r] - m_i[r]);
                Ps[wv * 16 + quad * 4 + r][t * 16 + fr] = f2bu(p);
                ls[r] += p;
            }
#pragma unroll
        for (int msk = 1; msk < 16; msk <<= 1)
#pragma unroll
            for (int r = 0; r < 4; r++) ls[r] += __shfl_xor(ls[r], msk);
#pragma unroll
        for (int r = 0; r < 4; r++) l_i[r] = l_i[r] * alpha[r] + ls[r];
#pragma unroll
        for (int t = 0; t < 4; t++)
#pragma unroll
            for (int r = 0; r < 4; r++) O[t][r] *= alpha[r];

#pragma unroll
        for (int ks = 0; ks < 4; ks++) {
            short8 ap = *(const short8*)&Ps[wv * 16 + fr][ks * 32 + q8];
#pragma unroll
            for (int t = 0; t < 4; t++) {
                short8 bv = *(const short8*)&Vts[t * 16 + fr][ks * 32 + q8];
                O[t] = __builtin_amdgcn_mfma_f32_16x16x32_bf16(ap, bv, O[t], 0, 0, 0);
            }
        }
    }

#pragma unroll
    for (int t = 0; t < 4; t++)
#pragma unroll
        for (int r = 0; r < 4; r++) {
            int q = qt * 64 + wv * 16 + quad * 4 + r;
            out[(bb + q) * 256 + h * 64 + t * 16 + fr] = f2bu(O[t][r] / l_i[r]);
        }
}

// out = LN(X + Y); optional bf16 duplicate. One block per row of 256.
__global__ void add_ln_kernel(const float* __restrict__ X, const float* __restrict__ Y,
                              const float* __restrict__ g, const float* __restrict__ bt,
                              float* __restrict__ out, u16* __restrict__ dup)
{
    int row = blockIdx.x;
    int t   = threadIdx.x;
    size_t idx = (size_t)row * DD + t;
    float v = X[idx] + Y[idx];
    __shared__ float red[DD];
    red[t] = v; __syncthreads();
    for (int s = 128; s > 0; s >>= 1) { if (t < s) red[t] += red[t + s]; __syncthreads(); }
    float m = red[0] * (1.f / DD);
    __syncthreads();
    float d = v - m;
    red[t] = d * d; __syncthreads();
    for (int s = 128; s > 0; s >>= 1) { if (t < s) red[t] += red[t + s]; __syncthreads(); }
    float var = red[0] * (1.f / DD);
    float o = d * rsqrtf(var + EPSF) * g[t] + bt[t];
    out[idx] = o;
    if (dup) dup[idx] = f2bu(o);
}

__global__ void pool_kernel(const float* __restrict__ enc, const int* __restrict__ lengths,
                            float* __restrict__ poolbuf)
{
    int b = blockIdx.x;
    int t = threadIdx.x;
    int L = lengths[b];
    if (L < 1) L = 1;
    const float* p = enc + (size_t)b * NN * DD + t;
    float s = 0.f, mx = -1e30f;
    for (int n = 0; n < NN; n++) {
        float v = p[(size_t)n * DD];
        s += v;
        if (n < L) mx = fmaxf(mx, v);
    }
    poolbuf[b * 512 + t]       = mx;
    poolbuf[b * 512 + 256 + t] = s / (float)L;
}

__global__ void head_kernel(const float* __restrict__ poolbuf, const float* __restrict__ lin_w,
                            const float* __restrict__ lin_b, const float* __restrict__ g,
                            const float* __restrict__ bt, float* __restrict__ out)
{
    int b = threadIdx.x;
    float r0 = lin_b[0], r1 = lin_b[1];
    for (int k = 0; k < 512; k++) {
        float p = poolbuf[b * 512 + k];
        r0 += p * lin_w[k];
        r1 += p * lin_w[512 + k];
    }
    __shared__ float s0[64], s1[64], mstat[4];
    s0[b] = r0; s1[b] = r1; __syncthreads();
    if (b == 0) {
        float a0 = 0, a1 = 0, q0 = 0, q1 = 0;
        for (int i = 0; i < 64; i++) { a0 += s0[i]; a1 += s1[i]; }
        a0 *= (1.f / 64.f); a1 *= (1.f / 64.f);
        for (int i = 0; i < 64; i++) {
            float d0 = s0[i] - a0, d1 = s1[i] - a1;
            q0 += d0 * d0; q1 += d1 * d1;
        }
        mstat[0] = a0; mstat[1] = a1; mstat[2] = q0 * (1.f / 64.f); mstat[3] = q1 * (1.f / 64.f);
    }
    __syncthreads();
    float z0 = (r0 - mstat[0]) * rsqrtf(mstat[2] + EPSF) * g[0] + bt[0];
    float z1 = (r1 - mstat[1]) * rsqrtf(mstat[3] + EPSF) * g[1] + bt[1];
    float mx = fmaxf(z0, z1);
    float e0 = __expf(z0 - mx), e1 = __expf(z1 - mx);
    float inv = 1.f / (e0 + e1);
    out[b * 2 + 0] = e0 * inv;
    out[b * 2 + 1] = e1 * inv;
}

extern "C" void kernel_launch(void* const* d_in, const int* in_sizes, int n_in,
                              void* d_out, int out_size, void* d_ws, size_t ws_size,
                              hipStream_t stream)
{
    (void)in_sizes; (void)n_in; (void)out_size; (void)ws_size;
    const float* x          = (const float*)d_in[0];
    const float* edge_attr  = (const float*)d_in[1];
    const float* W1         = (const float*)d_in[5];
    const float* W2         = (const float*)d_in[6];
    const float* W3         = (const float*)d_in[7];
    const float* b3         = (const float*)d_in[8];
    const float* gcn_bias   = (const float*)d_in[9];
    const float* bn1_g      = (const float*)d_in[10];
    const float* bn1_b      = (const float*)d_in[11];
    const float* in_proj_w  = (const float*)d_in[12];
    const float* in_proj_b  = (const float*)d_in[13];
    const float* out_proj_w = (const float*)d_in[14];
    const float* out_proj_b = (const float*)d_in[15];
    const float* ln1_g      = (const float*)d_in[16];
    const float* ln1_b      = (const float*)d_in[17];
    const float* lin1_w     = (const float*)d_in[18];
    const float* lin1_b     = (const float*)d_in[19];
    const float* lin2_w     = (const float*)d_in[20];
    const float* lin2_b     = (const float*)d_in[21];
    const float* ln2_g      = (const float*)d_in[22];
    const float* ln2_b      = (const float*)d_in[23];
    const float* bn2_g      = (const float*)d_in[24];
    const float* bn2_b      = (const float*)d_in[25];
    const float* lin_w      = (const float*)d_in[26];
    const float* lin_b      = (const float*)d_in[27];
    const float* bn3_g      = (const float*)d_in[28];
    const float* bn3_b      = (const float*)d_in[29];

    // ---- Workspace layout (~185 MB) ----
    char* p = (char*)d_ws;
    u16*   big   = (u16*)p;   p += (size_t)BN_TOT * 1024 * 2;   // 64 MiB
    float* bufA  = (float*)p; p += (size_t)BN_TOT * 256 * 4;    // aggM/h -> ffb
    float* bufB  = (float*)p; p += (size_t)BN_TOT * 256 * 4;    // y1 -> attnp -> h2
    float* bufC  = (float*)p; p += (size_t)BN_TOT * 256 * 4;    // agg1 -> h1
    u16*   bufP  = (u16*)p;   p += (size_t)BN_TOT * 256 * 2;    // hb -> attnoutb -> h1b
    float* deg   = (float*)p; p += (size_t)BN_TOT * 4;
    u16*   Mb    = (u16*)p;   p += 256 * 64 * 2;
    float* sb    = (float*)p; p += 1024;
    float* stats = (float*)p; p += 4 * 256 * 4;
    float* poolbuf=(float*)p; p += 64 * 512 * 4;
    int*   flags = (int*)p;   p += 256;
    int*   erc   = (int*)p;   p += BE_TOT * 4;
    int*   ecc   = (int*)p;   p += BE_TOT * 4;
    int*   lenc  = (int*)p;   p += 256;
    int*   sorted= (int*)p;   p += BE_TOT * 4;
    int*   noff  = (int*)p;   p += BN_TOT * 4;
    u16*   W1b   = (u16*)p;   p += 256 * 320 * 2;
    u16*   W3ab  = (u16*)p;   p += 256 * 256 * 2;
    u16*   ipwb  = (u16*)p;   p += 768 * 256 * 2;
    u16*   opwb  = (u16*)p;   p += 256 * 256 * 2;
    u16*   l1wb  = (u16*)p;   p += 1024 * 256 * 2;
    u16*   l2wb  = (u16*)p;   p += 256 * 1024 * 2;

    // bf16 temporaries inside big:
    //  phase 1 (pre-attn): [xb 320 | xsb 256 | eaggb 64] cols
    //  phase 2: qkb (512 cols) + vtb (256 cols worth) ; phase 3: ffa (1024 cols)
    u16* xb    = big;                              // 32768 x 320
    u16* xsb   = big + (size_t)BN_TOT * 320;       // 32768 x 256
    u16* eaggb = big + (size_t)BN_TOT * (320+256); // 32768 x 64
    u16* qkb   = big;                              // 32768 x 512
    u16* vtb   = big + (size_t)BN_TOT * 512;       // [b,h,d,node] = 32768 x 256
    bf16* ffa  = (bf16*)big;

    float* y1      = bufB;
    float* agg1    = bufC;
    float* aggM    = bufA;    // becomes h in finalize
    float* h       = bufA;
    u16*   hb      = bufP;
    u16*   attnoutb= bufP;    // hb dead after in_proj GEMM
    float* attnp   = bufB;    // y1 dead after finalize
    float* h1      = bufC;    // agg1 dead after finalize
    u16*   h1b     = bufP;    // attnoutb dead after out_proj GEMM
    float* ffb     = bufA;    // h dead after add_ln #1
    float* h2      = bufB;    // attnp dead after add_ln #1

    hipMemsetAsync(stats, 0, 4 * 256 * 4, stream);

    detect_kernel<<<1, 1, 0, stream>>>((const int*)d_in[4], flags);
    conv_i<<<(BE_TOT + 255) / 256, 256, 0, stream>>>(d_in[2], erc, BE_TOT, flags);
    conv_i<<<(BE_TOT + 255) / 256, 256, 0, stream>>>(d_in[3], ecc, BE_TOT, flags);
    conv_i<<<1, 64, 0, stream>>>(d_in[4], lenc, BB, flags);

    conv_pad<<<(BN_TOT * 320 + 255) / 256, 256, 0, stream>>>(x, xb, BN_TOT, FINK, 320);
    conv_pad<<<(256 * 320 + 255) / 256, 256, 0, stream>>>(W1, W1b, 256, FINK, 320);
    conv_w3a<<<256, 256, 0, stream>>>(W3, W3ab);
    conv_f2b<<<(768 * 256 + 255) / 256, 256, 0, stream>>>(in_proj_w, ipwb, 768 * 256);
    conv_f2b<<<(256 * 256 + 255) / 256, 256, 0, stream>>>(out_proj_w, opwb, 256 * 256);
    conv_f2b<<<(1024 * 256 + 255) / 256, 256, 0, stream>>>(lin1_w, l1wb, 1024 * 256);
    conv_f2b<<<(256 * 1024 + 255) / 256, 256, 0, stream>>>(lin2_w, l2wb, 256 * 1024);

    prep_M<<<256, 64, 0, stream>>>(W3, W2, Mb, sb);
    sort_edges<<<BB, 512, 0, stream>>>(ecc, deg, noff, sorted);

    // xs = x @ W1.T  (bf16 out, K padded to 320)
    gemm_bf<bf16, 0><<<dim3(2, 256), 256, 0, stream>>>(
        xb, W1b, nullptr, (bf16*)xsb, nullptr, BN_TOT, 256, 320, 320, 320);
    // y1 = xs @ W3a.T + b3
    gemm_bf<float, 0><<<dim3(2, 256), 256, 0, stream>>>(
        xsb, W3ab, b3, y1, nullptr, BN_TOT, 256, 256, 256, 256);

    edge_gather<<<BN_TOT, 256, 0, stream>>>(erc, sorted, noff, deg, y1, edge_attr, agg1, eaggb);
    gemm_bf<float, 0><<<dim3(2, 256), 256, 0, stream>>>(
        eaggb, Mb, nullptr, aggM, nullptr, BN_TOT, 256, 64, 64, 64);

    gcn_finalize<<<BN_TOT, 256, 0, stream>>>(agg1, aggM, y1, sb, deg, gcn_bias, lenc);

    bn_stats<<<512, 256, 0, stream>>>(h, stats, stats + 256, BN_TOT);
    bn_apply<<<BN_TOT, 256, 0, stream>>>(h, stats, stats + 256, bn1_g, bn1_b, BN_TOT, hb);

    // qkv projection with split epilogue: qkb row-major, V transposed to vtb
    gemm_bf<bf16, 2><<<dim3(6, 256), 256, 0, stream>>>(
        hb, ipwb, in_proj_b, (bf16*)qkb, vtb, BN_TOT, 768, 256, 256, 256);

    attn_mfma<<<2048, 256, 0, stream>>>(qkb, vtb, attnoutb);

    gemm_bf<float, 0><<<dim3(2, 256), 256, 0, stream>>>(
        attnoutb, opwb, out_proj_b, attnp, nullptr, BN_TOT, 256, 256, 256, 256);

    add_ln_kernel<<<BN_TOT, 256, 0, stream>>>(h, attnp, ln1_g, ln1_b, h1, h1b);

    gemm_bf<bf16, 1><<<dim3(8, 256), 256, 0, stream>>>(
        h1b, l1wb, lin1_b, ffa, nullptr, BN_TOT, 1024, 256, 256, 256);
    gemm_bf<float, 0><<<dim3(2, 256), 256, 0, stream>>>(
        (const u16*)ffa, l2wb, lin2_b, ffb, nullptr, BN_TOT, 256, 1024, 1024, 1024);

    add_ln_kernel<<<BN_TOT, 256, 0, stream>>>(h1, ffb, ln2_g, ln2_b, h2, nullptr);

    bn_stats<<<512, 256, 0, stream>>>(h2, stats + 512, stats + 768, BN_TOT);
    bn_apply<<<BN_TOT, 256, 0, stream>>>(h2, stats + 512, stats + 768, bn2_g, bn2_b, BN_TOT, nullptr);

    pool_kernel<<<64, 256, 0, stream>>>(h2, lenc, poolbuf);
    head_kernel<<<1, 64, 0, stream>>>(poolbuf, lin_w, lin_b, bn3_g, bn3_b, (float*)d_out);
}